// Round 6
// baseline (129.597 us; speedup 1.0000x reference)
//
#include <hip/hip_runtime.h>
#include <hip/hip_bf16.h>
#include <cstdint>
#include <cstddef>

// Problem dims (fixed): B=4, NI=NO=256, DIN=DQ=DH=DOUT=256.
// out[b,i,j,:] = gelu(u[b,i,:] + v[b,j,:]) @ W2 + b2
//   u = (x@W_pre + b_pre)@W1[:256] + b1   (b1 folded into u)
//   v = (query@W_emb + b_emb)@W1[256:]

typedef __bf16  bf16x8 __attribute__((ext_vector_type(8)));
typedef float   f32x16 __attribute__((ext_vector_type(16)));

// tanh-approx gelu with exp2 constant pre-folded:
// gelu(x) ~= x / (1 + exp2(x*(-2.3022072 - 0.1029433*x^2)))
__device__ __forceinline__ float fast_gelu(float x) {
    const float x2 = x * x;
    const float m  = __builtin_fmaf(x2, -0.1029433f, -2.3022072f);
    const float e  = __builtin_amdgcn_exp2f(x * m);
    return x * __builtin_amdgcn_rcpf(1.0f + e);
}

// ---------------------------------------------------------------------------
// Prep kernel (one launch):
//   blocks [0,256):   u rows — x path (4 rows/block)
//   blocks [256,512): v rows — query path
//   blocks [512,576): W2T[n][k] = bf16(W2[k][n])  (4 n-cols/block)
// ---------------------------------------------------------------------------
__global__ __launch_bounds__(256) void prep_kernel(
    const float* __restrict__ x, const float* __restrict__ query,
    const float* __restrict__ W_pre, const float* __restrict__ b_pre,
    const float* __restrict__ W_emb, const float* __restrict__ b_emb,
    const float* __restrict__ W1, const float* __restrict__ b1,
    const float* __restrict__ W2,
    float* __restrict__ u, float* __restrict__ v,
    unsigned short* __restrict__ w2t)
{
    const int b = blockIdx.x;
    const int t = threadIdx.x;

    if (b >= 512) {                       // W2 transpose + bf16 convert
        const int n0 = (b - 512) * 4;
        const float4 wv = *reinterpret_cast<const float4*>(W2 + (size_t)t * 256 + n0);
        const float vals[4] = {wv.x, wv.y, wv.z, wv.w};
#pragma unroll
        for (int j = 0; j < 4; ++j) {
            const __bf16 bv = (__bf16)vals[j];
            w2t[(size_t)(n0 + j) * 256 + t] = __builtin_bit_cast(unsigned short, bv);
        }
        return;
    }

    const bool isq = (b >= 256);
    const float* __restrict__ A   = isq ? query : x;
    const float* __restrict__ Wa  = isq ? W_emb : W_pre;
    const float* __restrict__ ba  = isq ? b_emb : b_pre;
    const float* __restrict__ W1p = isq ? (W1 + 256 * 256) : W1;
    float* __restrict__ outp      = isq ? v : u;
    const int r0 = (isq ? (b - 256) : b) * 4;

    __shared__ float as[4][256];
    __shared__ float xs[4][256];

#pragma unroll
    for (int r = 0; r < 4; ++r)
        as[r][t] = A[(size_t)(r0 + r) * 256 + t];
    __syncthreads();

    float acc[4] = {0.f, 0.f, 0.f, 0.f};
    for (int k = 0; k < 256; ++k) {
        const float wv = Wa[(size_t)k * 256 + t];
#pragma unroll
        for (int r = 0; r < 4; ++r) acc[r] += as[r][k] * wv;
    }
    const float bav = ba[t];
#pragma unroll
    for (int r = 0; r < 4; ++r) xs[r][t] = acc[r] + bav;
    __syncthreads();

    float acc2[4] = {0.f, 0.f, 0.f, 0.f};
    for (int k = 0; k < 256; ++k) {
        const float wv = W1p[(size_t)k * 256 + t];
#pragma unroll
        for (int r = 0; r < 4; ++r) acc2[r] += xs[r][k] * wv;
    }
    const float b1v = isq ? 0.f : b1[t];
#pragma unroll
    for (int r = 0; r < 4; ++r)
        outp[(size_t)(r0 + r) * 256 + t] = acc2[r] + b1v;
}

// ---------------------------------------------------------------------------
// Fused main kernel — barrier-free main loop.
// Block = 256 threads = 4 waves; covers 128 j-rows x 128 cols of one (b,i)
// tile. Grid = 1024 tiles x 4 quadrants = 4096 blocks.
//   tile = bid>>2; jh = (bid>>1)&1 (row half); ch = bid&1 (col half).
// Wave w owns rows [jh*128 + w*32, +32) x cols [ch*128, +128):
//   acc = 4 x f32x16 = 64 VGPR.
//
// LDS: ONLY W2T col-half [128 n][256 k] bf16 = 64 KB, staged once per block
// via global_load_lds w16 (linear dest, inverse-swizzled source granule),
// then ONE __syncthreads. Main loop (16 k-steps of 16) has NO barriers:
// A-frags = gelu(u+v) computed per-lane in registers (once per H element
// within the block); B-frags via swizzled ds_read_b128 (2-way max = free,
// same pattern measured 0 conflicts in rounds 1-5).
// 64 KB LDS + ~130 VGPR -> 2 resident blocks/CU = 8 fully independent
// waves/CU: staging + V-load + store latency of one block hides under the
// other's MFMA/VALU. No lockstep convoy.
//
// mfma_f32_32x32x16_bf16 layouts (gfx950):
//   A: lane l holds A[l&31][(l>>5)*8 + e]
//   B: lane l holds B[(l>>5)*8 + e][l&31]
//   D: lane l reg r holds D[(r&3) + 8*(r>>2) + 4*(l>>5)][l&31]
// ---------------------------------------------------------------------------
__global__ __launch_bounds__(256, 2) void fused_kernel(
    const float* __restrict__ U, const float* __restrict__ V,
    const unsigned short* __restrict__ W2T, const float* __restrict__ b2,
    float* __restrict__ out)
{
    __shared__ uint4 wlds[4096];   // 64 KB: [128 n][32 granules], swizzled

    const int t    = threadIdx.x;
    const int lane = t & 63;
    const int w    = t >> 6;       // 0..3
    const int l31  = lane & 31;
    const int hi   = lane >> 5;    // 0..1

    const int bid  = blockIdx.x;
    const int tile = bid >> 2;     // 0..1023 = (bb, ii)
    const int jh   = (bid >> 1) & 1;
    const int ch   = bid & 1;
    const int bb   = tile >> 8;
    const int n0   = ch * 128;     // col base
    const int j0   = jh * 128;     // row base

    // ---- stage W2T col-half once: 4096 granules, 16 per thread ----
#pragma unroll
    for (int it = 0; it < 16; ++it) {
        const int idx = it * 256 + t;            // linear LDS granule
        const int n   = idx >> 5;                // 0..127 (local col)
        const int gp  = idx & 31;                // LDS granule slot
        const int g   = (gp & 24) | ((gp ^ n) & 7);  // inverse-swizzled src
        __builtin_amdgcn_global_load_lds(
            (const __attribute__((address_space(1))) unsigned int*)
                (W2T + (size_t)(n0 + n) * 256 + g * 8),
            (__attribute__((address_space(3))) unsigned int*)(wlds + idx),
            16, 0, 0);
    }

    const float* __restrict__ urow = U + (size_t)tile * 256;
    const float* __restrict__ vrow =
        V + ((size_t)(bb * 256 + j0 + w * 32 + l31)) * 256;

    f32x16 acc[4];
#pragma unroll
    for (int i = 0; i < 4; ++i) acc[i] = (f32x16)0.f;

    __syncthreads();   // drains global_load_lds; the ONLY block-wide barrier

    // ---- barrier-free main loop: 16 k-steps of 16 ----
#pragma unroll 4
    for (int s = 0; s < 16; ++s) {
        const int k0 = s * 16 + hi * 8;
        const float4 ua = *reinterpret_cast<const float4*>(urow + k0);
        const float4 ub = *reinterpret_cast<const float4*>(urow + k0 + 4);
        const float4 va = *reinterpret_cast<const float4*>(vrow + k0);
        const float4 vb = *reinterpret_cast<const float4*>(vrow + k0 + 4);

        bf16x8 afrag;
        afrag[0] = (__bf16)fast_gelu(ua.x + va.x);
        afrag[1] = (__bf16)fast_gelu(ua.y + va.y);
        afrag[2] = (__bf16)fast_gelu(ua.z + va.z);
        afrag[3] = (__bf16)fast_gelu(ua.w + va.w);
        afrag[4] = (__bf16)fast_gelu(ub.x + vb.x);
        afrag[5] = (__bf16)fast_gelu(ub.y + vb.y);
        afrag[6] = (__bf16)fast_gelu(ub.z + vb.z);
        afrag[7] = (__bf16)fast_gelu(ub.w + vb.w);

        const int gk = 2 * s + hi;               // k-granule 0..31
#pragma unroll
        for (int cg = 0; cg < 4; ++cg) {
            const int nloc = cg * 32 + l31;      // local col 0..127
            const int slot = (gk & 24) | ((gk ^ nloc) & 7);
            const bf16x8 bfrag = __builtin_bit_cast(
                bf16x8, wlds[nloc * 32 + slot]);
            acc[cg] = __builtin_amdgcn_mfma_f32_32x32x16_bf16(
                afrag, bfrag, acc[cg], 0, 0, 0);
        }
    }

    // ---- epilogue: out[row][col] = acc + b2[col], nontemporal ----
    const size_t obase = (size_t)tile << 16;
#pragma unroll
    for (int cg = 0; cg < 4; ++cg) {
        const int col = n0 + cg * 32 + l31;
        const float bv = b2[col];
#pragma unroll
        for (int rr = 0; rr < 16; ++rr) {
            const int row = j0 + w * 32 + 4 * hi + (rr & 3) + 8 * (rr >> 2);
            __builtin_nontemporal_store(acc[cg][rr] + bv,
                                        out + obase + (size_t)row * 256 + col);
        }
    }
}

// ---------------------------------------------------------------------------
extern "C" void kernel_launch(void* const* d_in, const int* in_sizes, int n_in,
                              void* d_out, int out_size, void* d_ws, size_t ws_size,
                              hipStream_t stream)
{
    const float* x     = (const float*)d_in[0];
    const float* query = (const float*)d_in[1];
    const float* W_pre = (const float*)d_in[2];
    const float* b_pre = (const float*)d_in[3];
    const float* W_emb = (const float*)d_in[4];
    const float* b_emb = (const float*)d_in[5];
    const float* W1    = (const float*)d_in[6];
    const float* b1    = (const float*)d_in[7];
    const float* W2    = (const float*)d_in[8];
    const float* b2    = (const float*)d_in[9];
    float* out = (float*)d_out;

    char* ws = (char*)d_ws;
    float* u            = (float*)(ws);                          // 1 MB
    float* v            = (float*)(ws + (1 << 20));              // 1 MB
    unsigned short* w2t = (unsigned short*)(ws + 2 * (1 << 20)); // 128 KB

    prep_kernel<<<576, 256, 0, stream>>>(x, query, W_pre, b_pre, W_emb, b_emb,
                                         W1, b1, W2, u, v, w2t);
    fused_kernel<<<4096, 256, 0, stream>>>(u, v, w2t, b2, out);
}